// Round 15
// baseline (193.901 us; speedup 1.0000x reference)
//
#include <hip/hip_runtime.h>
#include <hip/hip_bf16.h>
#include <math.h>

#define N_NODES 50000
#define N_EDGES 800000
#define IN_DIM  128
#define OUT_DIM 64
#define LEAKY   0.01f

#define PROJ_ROWS 64
#define PROJ_NB   ((N_NODES + PROJ_ROWS - 1) / PROJ_ROWS)   // 782
#define EDGE_NB   ((N_EDGES + 255) / 256)                   // 3125

#define SCAN_B   1024
#define SCAN_NB  ((N_NODES + SCAN_B - 1) / SCAN_B)          // 49

// native 2x float vector -- accepted by __builtin_nontemporal_store
typedef float vfloat2 __attribute__((ext_vector_type(2)));

// ---------------------------------------------------------------------------
// FUSED: blocks [0, PROJ_NB) do z = feat @ W (+az epilogue);
//        blocks [PROJ_NB, ...) do degree histogram + coalesced rank write.
// (R7/R10/R12: this kernel is pinned ~53us by the 800k atomic-with-return
//  ops at the coherent point; proj rides in their shadow.)
__global__ __launch_bounds__(256) void proj_hist_kernel(
        const float* __restrict__ feat, const float* __restrict__ W,
        const float* __restrict__ a,
        __hip_bfloat16* __restrict__ zb,
        float* __restrict__ az_src, float* __restrict__ az_dst,
        const int* __restrict__ dst, int* __restrict__ counts,
        int* __restrict__ rank) {
    __shared__ float fs[PROJ_ROWS * IN_DIM];                // 32 KB
    int tid = threadIdx.x;

    if (blockIdx.x >= PROJ_NB) {
        int i = (blockIdx.x - PROJ_NB) * 256 + tid;
        if (i < N_EDGES) rank[i] = atomicAdd(&counts[dst[i]], 1);
        return;
    }

    // ---- projection: thread owns 4 rows x 4 cols; kk-rotation by row-group
    //      keeps ds_read_b128 conflict-free (R12: conflicts -> 0)
    int row0 = blockIdx.x * PROJ_ROWS;
    int nrows = N_NODES - row0; if (nrows > PROJ_ROWS) nrows = PROJ_ROWS;

    const float4* gsrc = (const float4*)(feat + (size_t)row0 * IN_DIM);
    if (nrows == PROJ_ROWS) {
#pragma unroll
        for (int i = 0; i < 8; ++i) {
            int idx = tid + i * 256;
            ((float4*)fs)[idx] = gsrc[idx];
        }
    } else {
        int lim = nrows * (IN_DIM / 4);
#pragma unroll
        for (int i = 0; i < 8; ++i) {
            int idx = tid + i * 256;
            if (idx < lim) ((float4*)fs)[idx] = gsrc[idx];
        }
    }
    __syncthreads();

    int lane  = tid & 63;
    int wv    = tid >> 6;
    int cg    = lane & 15;         // col group: cols cg*4 .. cg*4+3
    int rg    = lane >> 4;         // row subgroup 0..3
    int rbase = wv * 16 + rg * 4;

    float acc[4][4];
#pragma unroll
    for (int r = 0; r < 4; ++r)
#pragma unroll
        for (int c = 0; c < 4; ++c) acc[r][c] = 0.f;

    const float* fr0 = &fs[rbase * IN_DIM];
    for (int kk = 0; kk < IN_DIM / 4; ++kk) {
        int kr = (kk + rg) & 31;   // bank-conflict-free rotation
        float4 w0 = *(const float4*)&W[(kr * 4 + 0) * OUT_DIM + cg * 4];
        float4 w1 = *(const float4*)&W[(kr * 4 + 1) * OUT_DIM + cg * 4];
        float4 w2 = *(const float4*)&W[(kr * 4 + 2) * OUT_DIM + cg * 4];
        float4 w3 = *(const float4*)&W[(kr * 4 + 3) * OUT_DIM + cg * 4];
#pragma unroll
        for (int r = 0; r < 4; ++r) {
            float4 f = *(const float4*)&fr0[r * IN_DIM + kr * 4];
            acc[r][0] = fmaf(f.x, w0.x, acc[r][0]);
            acc[r][1] = fmaf(f.x, w0.y, acc[r][1]);
            acc[r][2] = fmaf(f.x, w0.z, acc[r][2]);
            acc[r][3] = fmaf(f.x, w0.w, acc[r][3]);
            acc[r][0] = fmaf(f.y, w1.x, acc[r][0]);
            acc[r][1] = fmaf(f.y, w1.y, acc[r][1]);
            acc[r][2] = fmaf(f.y, w1.z, acc[r][2]);
            acc[r][3] = fmaf(f.y, w1.w, acc[r][3]);
            acc[r][0] = fmaf(f.z, w2.x, acc[r][0]);
            acc[r][1] = fmaf(f.z, w2.y, acc[r][1]);
            acc[r][2] = fmaf(f.z, w2.z, acc[r][2]);
            acc[r][3] = fmaf(f.z, w2.w, acc[r][3]);
            acc[r][0] = fmaf(f.w, w3.x, acc[r][0]);
            acc[r][1] = fmaf(f.w, w3.y, acc[r][1]);
            acc[r][2] = fmaf(f.w, w3.z, acc[r][2]);
            acc[r][3] = fmaf(f.w, w3.w, acc[r][3]);
        }
    }

    float4 a1 = *(const float4*)&a[cg * 4];
    float4 a2 = *(const float4*)&a[OUT_DIM + cg * 4];
#pragma unroll
    for (int r = 0; r < 4; ++r) {
        int row = row0 + rbase + r;
        if (row < N_NODES) {
            __hip_bfloat16 z0 = __float2bfloat16(acc[r][0]);
            __hip_bfloat16 z1 = __float2bfloat16(acc[r][1]);
            __hip_bfloat16 z2 = __float2bfloat16(acc[r][2]);
            __hip_bfloat16 z3 = __float2bfloat16(acc[r][3]);
            ushort4 zp;
            zp.x = *(unsigned short*)&z0;
            zp.y = *(unsigned short*)&z1;
            zp.z = *(unsigned short*)&z2;
            zp.w = *(unsigned short*)&z3;
            *(ushort4*)&zb[(size_t)row * OUT_DIM + cg * 4] = zp;

            float s1 = acc[r][0] * a1.x + acc[r][1] * a1.y +
                       acc[r][2] * a1.z + acc[r][3] * a1.w;
            float s2 = acc[r][0] * a2.x + acc[r][1] * a2.y +
                       acc[r][2] * a2.z + acc[r][3] * a2.w;
#pragma unroll
            for (int off = 1; off < 16; off <<= 1) {
                s1 += __shfl_xor(s1, off, 64);
                s2 += __shfl_xor(s2, off, 64);
            }
            if (cg == 0) { az_src[row] = s1; az_dst[row] = s2; }
        }
    }
}

// ---------------------------------------------------------------------------
// scan: per-block exclusive scan of counts + 49 block totals. Consumers
// (build, node) add the block prefix themselves -- scan3 kernel deleted.
__global__ __launch_bounds__(SCAN_B) void scan1_kernel(
        const int* __restrict__ counts, int* __restrict__ offsets,
        int* __restrict__ blocksums) {
    __shared__ int s[SCAN_B];
    int i = blockIdx.x * SCAN_B + threadIdx.x;
    int v = (i < N_NODES) ? counts[i] : 0;
    s[threadIdx.x] = v;
    __syncthreads();
    for (int off = 1; off < SCAN_B; off <<= 1) {
        int t = (threadIdx.x >= off) ? s[threadIdx.x - off] : 0;
        __syncthreads();
        s[threadIdx.x] += t;
        __syncthreads();
    }
    if (i < N_NODES) offsets[i] = s[threadIdx.x] - v;   // block-local exclusive
    if (threadIdx.x == SCAN_B - 1) blocksums[blockIdx.x] = s[SCAN_B - 1];
}

// shared preamble: wave 0 scans the 49 blocksums into LDS bs[] (exclusive)
__device__ __forceinline__ void load_block_prefix(
        const int* __restrict__ blocksums, int* bs) {
    if (threadIdx.x < 64) {
        int lane = threadIdx.x;
        int v = (lane < SCAN_NB) ? blocksums[lane] : 0;
        int inc = v;
#pragma unroll
        for (int off = 1; off < 64; off <<= 1) {
            int t = __shfl_up(inc, off, 64);
            if (lane >= off) inc += t;
        }
        bs[lane] = inc - v;
    }
    __syncthreads();
}

// ---------------------------------------------------------------------------
// CSR build, atomic-free: pos = offsets[t] + bs[t>>10] + rank. Emits an 8B
// record (src, az_src[src]) per edge via NON-TEMPORAL store.
__global__ __launch_bounds__(256) void build_csr_kernel(
        const int* __restrict__ src, const int* __restrict__ dst,
        const int* __restrict__ rank, const int* __restrict__ offsets,
        const int* __restrict__ blocksums,
        const float* __restrict__ az_src, vfloat2* __restrict__ edge_rec) {
    __shared__ int bs[64];
    load_block_prefix(blocksums, bs);
    int i = blockIdx.x * 256 + threadIdx.x;
    if (i >= N_EDGES) return;
    int t = dst[i];
    int s = src[i];
    int pos = offsets[t] + bs[t >> 10] + rank[i];   // offsets L2-hot
    vfloat2 rec;
    rec.x = __int_as_float(s);
    rec.y = az_src[s];                              // 200KB L2-hot gather
    __builtin_nontemporal_store(rec, &edge_rec[pos]);
}

// ---------------------------------------------------------------------------
// single-pass softmax-aggregation. One wave per node, lane = dim.
// Per edge: one 8B record + one 128B z-row gather; 8 independent load chains
// (avg degree 16 -> 2 main-loop iterations with 16 loads in flight).
__global__ __launch_bounds__(256) void node_fused_kernel(
        const int* __restrict__ offsets, const int* __restrict__ blocksums,
        const vfloat2* __restrict__ edge_rec,
        const float* __restrict__ az_dst,
        const __hip_bfloat16* __restrict__ zb, float* __restrict__ h) {
    __shared__ int bs[64];
    load_block_prefix(blocksums, bs);
    int lane = threadIdx.x & 63;
    int w    = threadIdx.x >> 6;
    int t    = blockIdx.x * 4 + w;
    if (t >= N_NODES) return;
    int beg = offsets[t] + bs[t >> 10];
    int end = (t + 1 < N_NODES) ? offsets[t + 1] + bs[(t + 1) >> 10] : N_EDGES;
    float az_d = az_dst[t];

    float ac0 = 0.f, ac1 = 0.f, ac2 = 0.f, ac3 = 0.f;
    float ac4 = 0.f, ac5 = 0.f, ac6 = 0.f, ac7 = 0.f;
    float sm0 = 0.f, sm1 = 0.f, sm2 = 0.f, sm3 = 0.f;
    float sm4 = 0.f, sm5 = 0.f, sm6 = 0.f, sm7 = 0.f;
    int k = beg;
    for (; k + 8 <= end; k += 8) {
        vfloat2 r0 = edge_rec[k];
        vfloat2 r1 = edge_rec[k + 1];
        vfloat2 r2 = edge_rec[k + 2];
        vfloat2 r3 = edge_rec[k + 3];
        vfloat2 r4 = edge_rec[k + 4];
        vfloat2 r5 = edge_rec[k + 5];
        vfloat2 r6 = edge_rec[k + 6];
        vfloat2 r7 = edge_rec[k + 7];
        float v0 = r0.y + az_d, v1 = r1.y + az_d;
        float v2 = r2.y + az_d, v3 = r3.y + az_d;
        float v4 = r4.y + az_d, v5 = r5.y + az_d;
        float v6 = r6.y + az_d, v7 = r7.y + az_d;
        v0 = v0 > 0.f ? v0 : LEAKY * v0;
        v1 = v1 > 0.f ? v1 : LEAKY * v1;
        v2 = v2 > 0.f ? v2 : LEAKY * v2;
        v3 = v3 > 0.f ? v3 : LEAKY * v3;
        v4 = v4 > 0.f ? v4 : LEAKY * v4;
        v5 = v5 > 0.f ? v5 : LEAKY * v5;
        v6 = v6 > 0.f ? v6 : LEAKY * v6;
        v7 = v7 > 0.f ? v7 : LEAKY * v7;
        float x0 = __expf(v0), x1 = __expf(v1);
        float x2 = __expf(v2), x3 = __expf(v3);
        float x4 = __expf(v4), x5 = __expf(v5);
        float x6 = __expf(v6), x7 = __expf(v7);
        sm0 += x0; sm1 += x1; sm2 += x2; sm3 += x3;
        sm4 += x4; sm5 += x5; sm6 += x6; sm7 += x7;
        int s0 = __float_as_int(r0.x), s1 = __float_as_int(r1.x);
        int s2 = __float_as_int(r2.x), s3 = __float_as_int(r3.x);
        int s4 = __float_as_int(r4.x), s5 = __float_as_int(r5.x);
        int s6 = __float_as_int(r6.x), s7 = __float_as_int(r7.x);
        ac0 = fmaf(x0, __bfloat162float(zb[(size_t)s0 * OUT_DIM + lane]), ac0);
        ac1 = fmaf(x1, __bfloat162float(zb[(size_t)s1 * OUT_DIM + lane]), ac1);
        ac2 = fmaf(x2, __bfloat162float(zb[(size_t)s2 * OUT_DIM + lane]), ac2);
        ac3 = fmaf(x3, __bfloat162float(zb[(size_t)s3 * OUT_DIM + lane]), ac3);
        ac4 = fmaf(x4, __bfloat162float(zb[(size_t)s4 * OUT_DIM + lane]), ac4);
        ac5 = fmaf(x5, __bfloat162float(zb[(size_t)s5 * OUT_DIM + lane]), ac5);
        ac6 = fmaf(x6, __bfloat162float(zb[(size_t)s6 * OUT_DIM + lane]), ac6);
        ac7 = fmaf(x7, __bfloat162float(zb[(size_t)s7 * OUT_DIM + lane]), ac7);
    }
    for (; k < end; ++k) {
        vfloat2 r0 = edge_rec[k];
        float v0 = r0.y + az_d;
        v0 = v0 > 0.f ? v0 : LEAKY * v0;
        float x0 = __expf(v0);
        sm0 += x0;
        int s0 = __float_as_int(r0.x);
        ac0 = fmaf(x0, __bfloat162float(zb[(size_t)s0 * OUT_DIM + lane]), ac0);
    }
    float ssum = ((sm0 + sm1) + (sm2 + sm3)) + ((sm4 + sm5) + (sm6 + sm7));
    float inv  = (end > beg) ? 1.f / ssum : 0.f;
    float hv   = ((ac0 + ac1) + (ac2 + ac3)) + ((ac4 + ac5) + (ac6 + ac7));
    h[(size_t)t * OUT_DIM + lane] = hv * inv;
}

// ---------------------------------------------------------------------------
extern "C" void kernel_launch(void* const* d_in, const int* in_sizes, int n_in,
                              void* d_out, int out_size, void* d_ws, size_t ws_size,
                              hipStream_t stream) {
    const float* feat = (const float*)d_in[0];
    const int*   src  = (const int*)  d_in[1];
    const int*   dst  = (const int*)  d_in[2];
    const float* W    = (const float*)d_in[3];
    const float* a    = (const float*)d_in[4];
    float* h = (float*)d_out;

    // workspace layout (8B-aligned edge_rec first)
    vfloat2* edge_rec = (vfloat2*)d_ws;                      // E vfloat2
    float*  az_src    = (float*)(edge_rec + N_EDGES);        // N
    float*  az_dst    = az_src + N_NODES;                    // N
    int*    counts    = (int*)(az_dst + N_NODES);            // N
    int*    offsets   = counts + N_NODES;                    // N (block-local)
    int*    blocksums = offsets + N_NODES;                   // 64
    int*    rank      = blocksums + 64;                      // E
    __hip_bfloat16* zb = (__hip_bfloat16*)(rank + N_EDGES);  // N*64

    (void)hipMemsetAsync(counts, 0, sizeof(int) * N_NODES, stream);

    proj_hist_kernel<<<PROJ_NB + EDGE_NB, 256, 0, stream>>>(
        feat, W, a, zb, az_src, az_dst, dst, counts, rank);

    scan1_kernel<<<SCAN_NB, SCAN_B, 0, stream>>>(counts, offsets, blocksums);

    build_csr_kernel<<<EDGE_NB, 256, 0, stream>>>(src, dst, rank, offsets,
                                                  blocksums, az_src, edge_rec);

    node_fused_kernel<<<(N_NODES + 3) / 4, 256, 0, stream>>>(
        offsets, blocksums, edge_rec, az_dst, zb, h);
}